// Round 7
// baseline (214.100 us; speedup 1.0000x reference)
//
#include <hip/hip_runtime.h>

// B=2, D=64, N=512, H=256, OUT=64
// mid[b] = sum_{c,i} relu( relu(hi[b,i,:]+hcb[b,c,:]) @ w2 + b2 ) @ w3 + N^2*b3
// out = relu(mid @ w4 + b4) @ w5 + b5
//
// big v7: wave = (c-octet x i-octet) 64 pairs x 64 cols. A generated per-kk into
// transient regs (8); B staged once per block in LDS (32 KB, fragment-ordered,
// linear ds_read_b128); acc = 4 x f32x16. No barriers in main loop.

using f32x16  = __attribute__((ext_vector_type(16))) float;
using short8  = __attribute__((ext_vector_type(8))) short;
using float4v = __attribute__((ext_vector_type(4))) float;

__device__ __forceinline__ short f2bf(float f) {
    unsigned u = __float_as_uint(f);
    unsigned r = u + 0x7FFFu + ((u >> 16) & 1u);   // RNE
    return (short)(r >> 16);
}

__device__ __forceinline__ short8 relu_pack8(float4v lo, float4v hi4) {
#pragma unroll
    for (int e = 0; e < 4; ++e) {
        lo[e]  = fmaxf(lo[e], 0.f);
        hi4[e] = fmaxf(hi4[e], 0.f);
    }
    union { short8 s; unsigned u[4]; } r;
    asm("v_cvt_pk_bf16_f32 %0, %1, %2" : "=v"(r.u[0]) : "v"(lo[0]),  "v"(lo[1]));
    asm("v_cvt_pk_bf16_f32 %0, %1, %2" : "=v"(r.u[1]) : "v"(lo[2]),  "v"(lo[3]));
    asm("v_cvt_pk_bf16_f32 %0, %1, %2" : "=v"(r.u[2]) : "v"(hi4[0]), "v"(hi4[1]));
    asm("v_cvt_pk_bf16_f32 %0, %1, %2" : "=v"(r.u[3]) : "v"(hi4[2]), "v"(hi4[3]));
    return r.s;
}

// ---- prep: blocks [0,1024): hi/hcb; blocks [1024,1280): fragment-ordered w2
__global__ __launch_bounds__(256) void prep(const float* __restrict__ in,
                                            const float* __restrict__ w1,
                                            const float* __restrict__ b1,
                                            const float* __restrict__ w2,
                                            float* __restrict__ hi,
                                            float* __restrict__ hcb,
                                            short* __restrict__ bfrag) {
    int tid = threadIdx.x;
    int bidx = blockIdx.x;
    if (bidx < 1024) {
        int b = bidx >> 9, n = bidx & 511;
        __shared__ float xs[64];
        if (tid < 64) xs[tid] = in[(size_t)(b * 64 + tid) * 512 + n];
        __syncthreads();
        float a0 = 0.f, a1 = 0.f;
#pragma unroll 8
        for (int d = 0; d < 64; ++d) {
            float xv = xs[d];
            a0 += xv * w1[d * 256 + tid];
            a1 += xv * w1[(64 + d) * 256 + tid];
        }
        size_t o = (size_t)(b * 512 + n) * 256 + tid;
        hi[o]  = a0;
        hcb[o] = a1 + b1[tid];
    } else {
        // off = (((ch*4+n4)*16+kk)*64 + h*32+col)*8 + j ; value bf16(w2[k][ncol])
        // k = 16kk+8h+j, ncol = ch*128 + n4*32 + col
        int idx = (bidx - 1024) * 256 + tid;        // [0, 65536)
        int k = idx >> 8, ncol = idx & 255;
        int ch = ncol >> 7, n4 = (ncol >> 5) & 3, col = ncol & 31;
        int kk = k >> 4, h = (k >> 3) & 1, j = k & 7;
        int off = ((((ch * 4 + n4) * 16 + kk) * 64) + h * 32 + col) * 8 + j;
        bfrag[off] = f2bf(w2[k * 256 + ncol]);
    }
}

// ---- big v7: 2048 blocks. bid -> (b, colgroup g, r6). Wave w: c-octet
// co=(r6>>4)*4+w; t-loop: i-octet io=(r6&15)*4+t.
__global__ __launch_bounds__(256, 3) void big(const float* __restrict__ hi_,
                                              const float* __restrict__ hcb_,
                                              const short8* __restrict__ bfrag,
                                              const float* __restrict__ b2,
                                              float* __restrict__ partials) {
    __shared__ __align__(16) short8 Blds[2048];   // [n][kk][lane] = 32 KB

    const int tid = threadIdx.x;
    const int bid = blockIdx.x;                   // [0,2048)
    const int b = bid >> 10, g = (bid >> 8) & 3, r6 = bid & 255;
    const int w = tid >> 6, lane = tid & 63;

    // stage B col-group (64 cols x 256 K), linear copy
    {
        const short8* __restrict__ src = bfrag + (size_t)(2 * g) * 1024;
#pragma unroll
        for (int q = 0; q < 8; ++q) Blds[q * 256 + tid] = src[q * 256 + tid];
    }
    __syncthreads();

    const int col = lane & 31, h = lane >> 5;
    const int cp = col >> 3;           // c' 0..3 (rows 0-31); rows 32-63 -> cp+4
    const int ip = lane & 7;

    const int co = (r6 >> 4) * 4 + w;
    const int baseio = (r6 & 15) * 4;

    const float* __restrict__ hcb0 = hcb_ + (size_t)b * 131072
                                   + (size_t)(co * 8 + cp) * 256 + 8 * h;
    const float* __restrict__ hcb1 = hcb0 + 4 * 256;
    const float* __restrict__ hibase = hi_ + (size_t)b * 131072
                                     + (size_t)(baseio * 8 + ip) * 256 + 8 * h;

    const float b2v0 = b2[g * 64 + col];
    const float b2v1 = b2[g * 64 + 32 + col];
    float psum0 = 0.f, psum1 = 0.f;

#pragma unroll 1
    for (int t = 0; t < 4; ++t) {
        const float* __restrict__ hirow = hibase + (size_t)t * (8 * 256);

        f32x16 A00, A01, A10, A11;    // [rowblock][ncolblock]
#pragma unroll
        for (int e = 0; e < 16; ++e) {
            A00[e] = b2v0; A01[e] = b2v1;
            A10[e] = b2v0; A11[e] = b2v1;
        }

#pragma unroll
        for (int kk = 0; kk < 16; ++kk) {
            float4v x0  = *reinterpret_cast<const float4v*>(hirow + 16 * kk);
            float4v x1  = *reinterpret_cast<const float4v*>(hirow + 16 * kk + 4);
            float4v c00 = *reinterpret_cast<const float4v*>(hcb0 + 16 * kk);
            float4v c01 = *reinterpret_cast<const float4v*>(hcb0 + 16 * kk + 4);
            float4v c10 = *reinterpret_cast<const float4v*>(hcb1 + 16 * kk);
            float4v c11 = *reinterpret_cast<const float4v*>(hcb1 + 16 * kk + 4);
            short8 a0 = relu_pack8(x0 + c00, x1 + c01);
            short8 a1 = relu_pack8(x0 + c10, x1 + c11);
            short8 bf0 = Blds[kk * 64 + lane];
            short8 bf1 = Blds[1024 + kk * 64 + lane];
            __builtin_amdgcn_s_setprio(1);
            A00 = __builtin_amdgcn_mfma_f32_32x32x16_bf16(a0, bf0, A00, 0, 0, 0);
            A01 = __builtin_amdgcn_mfma_f32_32x32x16_bf16(a0, bf1, A01, 0, 0, 0);
            A10 = __builtin_amdgcn_mfma_f32_32x32x16_bf16(a1, bf0, A10, 0, 0, 0);
            A11 = __builtin_amdgcn_mfma_f32_32x32x16_bf16(a1, bf1, A11, 0, 0, 0);
            __builtin_amdgcn_s_setprio(0);
        }

        float s0 = 0.f, s1 = 0.f;
#pragma unroll
        for (int e = 0; e < 16; ++e) {
            s0 += fmaxf(A00[e], 0.f) + fmaxf(A10[e], 0.f);
            s1 += fmaxf(A01[e], 0.f) + fmaxf(A11[e], 0.f);
        }
        psum0 += s0;
        psum1 += s1;
    }

    psum0 += __shfl_xor(psum0, 32);
    psum1 += __shfl_xor(psum1, 32);
    if (h == 0) {
        float* prow = partials + ((size_t)bid * 4 + w) * 64;
        prow[col]      = psum0;
        prow[32 + col] = psum1;
    }
}

// ---- reduceK: 64 blocks x 64 thr; block (bg 0..7, c8 0..7) sums 128 rows
__global__ __launch_bounds__(64) void reduceK(const float* __restrict__ partials,
                                              float* __restrict__ stage2) {
    int col = threadIdx.x, blk = blockIdx.x;
    int bg = blk >> 3, c8 = blk & 7;
    size_t base = ((size_t)bg * 1024 + (size_t)c8 * 128) * 64;
    float s = 0.f;
#pragma unroll 8
    for (int r = 0; r < 128; ++r) s += partials[base + (size_t)r * 64 + col];
    stage2[((size_t)bg * 8 + c8) * 64 + col] = s;
}

// ---- final tail: both batches in parallel (512 threads)
__global__ __launch_bounds__(512) void finalK(const float* __restrict__ stage2,
                                              const float* __restrict__ w3,
                                              const float* __restrict__ b3,
                                              const float* __restrict__ w4,
                                              const float* __restrict__ b4,
                                              const float* __restrict__ w5,
                                              const float* __restrict__ b5,
                                              float* __restrict__ out) {
    __shared__ float su[2][256], mid[2][256], o[2][256];
    int tid = threadIdx.x;
    int b = tid >> 8, c = tid & 255;
    int bg = b * 4 + (c >> 6), cl = c & 63;
    float s = 0.f;
#pragma unroll
    for (int c8 = 0; c8 < 8; ++c8) s += stage2[((size_t)bg * 8 + c8) * 64 + cl];
    su[b][c] = s;
    __syncthreads();
    float m = 262144.0f * b3[c];
    for (int k = 0; k < 256; ++k) m += su[b][k] * w3[k * 256 + c];
    mid[b][c] = m;
    __syncthreads();
    float ov = b4[c];
    for (int k = 0; k < 256; ++k) ov += mid[b][k] * w4[k * 256 + c];
    o[b][c] = fmaxf(ov, 0.f);
    __syncthreads();
    if (c < 64) {
        float r = b5[c];
        for (int k = 0; k < 256; ++k) r += o[b][k] * w5[k * 64 + c];
        out[b * 64 + c] = r;
    }
}

extern "C" void kernel_launch(void* const* d_in, const int* in_sizes, int n_in,
                              void* d_out, int out_size, void* d_ws, size_t ws_size,
                              hipStream_t stream) {
    const float* in = (const float*)d_in[0];
    const float* w1 = (const float*)d_in[1];
    const float* b1 = (const float*)d_in[2];
    const float* w2 = (const float*)d_in[3];
    const float* b2 = (const float*)d_in[4];
    const float* w3 = (const float*)d_in[5];
    const float* b3 = (const float*)d_in[6];
    const float* w4 = (const float*)d_in[7];
    const float* b4 = (const float*)d_in[8];
    const float* w5 = (const float*)d_in[9];
    const float* b5 = (const float*)d_in[10];
    float* out = (float*)d_out;

    char* ws = (char*)d_ws;
    float* hi       = (float*)(ws);                                    // 1 MB
    float* hcb      = (float*)(ws + (1u << 20));                       // 1 MB
    short* bfrag    = (short*)(ws + (2u << 20));                       // 128 KB
    float* partials = (float*)(ws + (2u << 20) + (256u << 10));        // 2 MB (8192x64)
    float* stage2   = (float*)(ws + (4u << 20) + (512u << 10));        // 16 KB

    prep<<<1280, 256, 0, stream>>>(in, w1, b1, w2, hi, hcb, bfrag);
    big<<<2048, 256, 0, stream>>>(hi, hcb, (const short8*)bfrag, b2, partials);
    reduceK<<<64, 64, 0, stream>>>(partials, stage2);
    finalK<<<1, 512, 0, stream>>>(stage2, w3, b3, w4, b4, w5, b5, out);
}

// Round 8
// 148.372 us; speedup vs baseline: 1.4430x; 1.4430x over previous
//
#include <hip/hip_runtime.h>

// B=2, D=64, N=512, H=256, OUT=64
// mid[b] = sum_{c,i} relu( relu(hi[b,i,:]+hcb[b,c,:]) @ w2 + b2 ) @ w3 + N^2*b3
// out = relu(mid @ w4 + b4) @ w5 + b5
//
// big v8 = R1 structure (B-in-VGPR, A in LDS dbuf, 1 barrier/tile) with gen
// split into 8 j-chunks interleaved between 8-MFMA octets (fine-grain overlap,
// tiny transient register state).

using f32x16  = __attribute__((ext_vector_type(16))) float;
using short8  = __attribute__((ext_vector_type(8))) short;
using float2v = __attribute__((ext_vector_type(2))) float;

__device__ __forceinline__ short f2bf(float f) {
    unsigned u = __float_as_uint(f);
    unsigned r = u + 0x7FFFu + ((u >> 16) & 1u);   // RNE
    return (short)(r >> 16);
}

// ---- prep (merged): blocks [0,1024): hi/hcb; blocks [1024,1280): w2t transpose
__global__ __launch_bounds__(256) void prep(const float* __restrict__ in,
                                            const float* __restrict__ w1,
                                            const float* __restrict__ b1,
                                            const float* __restrict__ w2,
                                            float* __restrict__ hi,
                                            float* __restrict__ hcb,
                                            short* __restrict__ w2t) {
    int tid = threadIdx.x;
    int bidx = blockIdx.x;
    if (bidx < 1024) {
        int b = bidx >> 9, n = bidx & 511;
        __shared__ float xs[64];
        if (tid < 64) xs[tid] = in[(size_t)(b * 64 + tid) * 512 + n];
        __syncthreads();
        float a0 = 0.f, a1 = 0.f;
#pragma unroll 8
        for (int d = 0; d < 64; ++d) {
            float xv = xs[d];
            a0 += xv * w1[d * 256 + tid];
            a1 += xv * w1[(64 + d) * 256 + tid];
        }
        size_t o = (size_t)(b * 512 + n) * 256 + tid;
        hi[o]  = a0;
        hcb[o] = a1 + b1[tid];
    } else {
        int idx = (bidx - 1024) * 256 + tid;
        int n = idx & 255, k = idx >> 8;
        w2t[n * 256 + k] = f2bf(w2[k * 256 + n]);
    }
}

// ---- big v8: 512 blocks x 16 tiles; j-chunk interleaved gen
__global__ __launch_bounds__(256, 2) void big(const float* __restrict__ hi,
                                              const float* __restrict__ hcb,
                                              const short* __restrict__ w2t,
                                              const float* __restrict__ b2,
                                              float* __restrict__ partials) {
    __shared__ __align__(16) unsigned tA[2][64 * 128];   // 2 x 32 KB

    const int tid = threadIdx.x;
    const int bid = blockIdx.x;                 // [0,512)
    const int b   = bid >> 8, rem = bid & 255;
    const int cc  = rem >> 2, icg = rem & 3;

    const float* __restrict__ hib  = hi  + (size_t)b * 131072;
    const float* __restrict__ hcbb = hcb + (size_t)b * 131072;

    const int cp   = tid & 127, half = tid >> 7;   // A-gen mapping
    const int lane = tid & 63,  wid  = tid >> 6;   // MFMA mapping
    const int h = lane >> 5, l31 = lane & 31, l7 = lane & 7;
    const int colbase = wid * 64;

    float2v cv2[4];
#pragma unroll
    for (int j = 0; j < 4; ++j)
        cv2[j] = *reinterpret_cast<const float2v*>(
            &hcbb[(size_t)(cc * 8 + half * 4 + j) * 256 + 2 * cp]);

    // persistent B fragments: 64 cols x K=256 bf16 per wave = 128 VGPRs
    short8 bfr[2][16];
    const short8* w2v = reinterpret_cast<const short8*>(w2t);
#pragma unroll
    for (int cf = 0; cf < 2; ++cf)
#pragma unroll
        for (int kk = 0; kk < 16; ++kk)
            bfr[cf][kk] = w2v[(size_t)(colbase + cf * 32 + l31) * 32 + kk * 2 + h];

    const float b2v0 = b2[colbase + l31];
    const float b2v1 = b2[colbase + 32 + l31];
    float psum0 = 0.f, psum1 = 0.f;

    const int cbase = cp >> 2, woff = cp & 3;

    // ---- prologue: generate tile 0 (full-tile gen, as in R1)
    {
        const float* hsrc0 = &hib[(size_t)(icg * 16 * 8) * 256 + 2 * cp];
        float2v hv2[8];
#pragma unroll
        for (int j = 0; j < 8; ++j)
            hv2[j] = *reinterpret_cast<const float2v*>(hsrc0 + (size_t)j * 256);
#pragma unroll
        for (int p = 0; p < 32; ++p) {
            float ax = hv2[p & 7][0] + cv2[p >> 3][0];
            float ay = hv2[p & 7][1] + cv2[p >> 3][1];
            ax = fmaxf(ax, 0.f);
            ay = fmaxf(ay, 0.f);
            unsigned pk;
            asm("v_cvt_pk_bf16_f32 %0, %1, %2" : "=v"(pk) : "v"(ax), "v"(ay));
            tA[0][(half * 32 + p) * 128 + (((cbase ^ (p & 7)) << 2) + woff)] = pk;
        }
    }
    __syncthreads();

#pragma unroll 1
    for (int t = 0; t < 16; ++t) {
        const int cur = t & 1;
        const short8* __restrict__ tAv = reinterpret_cast<const short8*>(tA[cur]);
        unsigned* __restrict__ wbuf = tA[cur ^ 1];
        const bool hn = (t < 15);
        const float* hsrc = &hib[(size_t)((icg * 16 + t + 1) * 8) * 256 + 2 * cp];

        f32x16 acc00, acc01, acc10, acc11;
#pragma unroll
        for (int e = 0; e < 16; ++e) {
            acc00[e] = b2v0; acc01[e] = b2v1;
            acc10[e] = b2v0; acc11[e] = b2v1;
        }

        float2v hvr[8];
        if (hn) {
            hvr[0] = *reinterpret_cast<const float2v*>(hsrc);
            hvr[1] = *reinterpret_cast<const float2v*>(hsrc + 256);
        }

#pragma unroll
        for (int j = 0; j < 8; ++j) {
            // issue load 2 chunks ahead (latency cover ~2 octets)
            if (hn && j < 6)
                hvr[j + 2] = *reinterpret_cast<const float2v*>(hsrc + (size_t)(j + 2) * 256);

            // MFMA octet: kk = 2j, 2j+1
#pragma unroll
            for (int e2 = 0; e2 < 2; ++e2) {
                const int kk = 2 * j + e2;
                const int sc = (kk * 2 + h) ^ l7;
                short8 a0 = tAv[l31 * 32 + sc];
                short8 a1 = tAv[(32 + l31) * 32 + sc];
                __builtin_amdgcn_s_setprio(1);
                acc00 = __builtin_amdgcn_mfma_f32_32x32x16_bf16(a0, bfr[0][kk], acc00, 0, 0, 0);
                acc01 = __builtin_amdgcn_mfma_f32_32x32x16_bf16(a0, bfr[1][kk], acc01, 0, 0, 0);
                acc10 = __builtin_amdgcn_mfma_f32_32x32x16_bf16(a1, bfr[0][kk], acc10, 0, 0, 0);
                acc11 = __builtin_amdgcn_mfma_f32_32x32x16_bf16(a1, bfr[1][kk], acc11, 0, 0, 0);
                __builtin_amdgcn_s_setprio(0);
            }

            // gen chunk j of tile t+1: rows {j, 8+j, 16+j, 24+j} (+32*half)
            if (hn) {
#pragma unroll
                for (int m = 0; m < 4; ++m) {
                    float ax = hvr[j][0] + cv2[m][0];
                    float ay = hvr[j][1] + cv2[m][1];
                    ax = fmaxf(ax, 0.f);
                    ay = fmaxf(ay, 0.f);
                    unsigned pk;
                    asm("v_cvt_pk_bf16_f32 %0, %1, %2" : "=v"(pk) : "v"(ax), "v"(ay));
                    wbuf[(half * 32 + m * 8 + j) * 128 + (((cbase ^ j) << 2) + woff)] = pk;
                }
            }
        }

        float s0 = 0.f, s1 = 0.f;
#pragma unroll
        for (int e = 0; e < 16; ++e) {
            s0 += fmaxf(acc00[e], 0.f) + fmaxf(acc10[e], 0.f);
            s1 += fmaxf(acc01[e], 0.f) + fmaxf(acc11[e], 0.f);
        }
        psum0 += s0;
        psum1 += s1;
        __syncthreads();
    }

    psum0 += __shfl_xor(psum0, 32);
    psum1 += __shfl_xor(psum1, 32);
    if (h == 0) {
        partials[(size_t)bid * 256 + colbase + l31]      = psum0;
        partials[(size_t)bid * 256 + colbase + 32 + l31] = psum1;
    }
}

// ---- final tail: both batches in parallel (512 threads)
__global__ __launch_bounds__(512) void finalK(const float* __restrict__ partials,
                                              const float* __restrict__ w3,
                                              const float* __restrict__ b3,
                                              const float* __restrict__ w4,
                                              const float* __restrict__ b4,
                                              const float* __restrict__ w5,
                                              const float* __restrict__ b5,
                                              float* __restrict__ out) {
    __shared__ float su[2][256], mid[2][256], o[2][256];
    int tid = threadIdx.x;
    int b = tid >> 8, col = tid & 255;
    const float* pb = partials + (size_t)b * 256 * 256;
    float s = 0.f;
#pragma unroll 8
    for (int r = 0; r < 256; ++r) s += pb[(size_t)r * 256 + col];
    su[b][col] = s;
    __syncthreads();
    float m = 262144.0f * b3[col];
    for (int k = 0; k < 256; ++k) m += su[b][k] * w3[k * 256 + col];
    mid[b][col] = m;
    __syncthreads();
    float ov = b4[col];
    for (int k = 0; k < 256; ++k) ov += mid[b][k] * w4[k * 256 + col];
    o[b][col] = fmaxf(ov, 0.f);
    __syncthreads();
    if (col < 64) {
        float r = b5[col];
        for (int k = 0; k < 256; ++k) r += o[b][k] * w5[k * 64 + col];
        out[b * 64 + col] = r;
    }
}

extern "C" void kernel_launch(void* const* d_in, const int* in_sizes, int n_in,
                              void* d_out, int out_size, void* d_ws, size_t ws_size,
                              hipStream_t stream) {
    const float* in = (const float*)d_in[0];
    const float* w1 = (const float*)d_in[1];
    const float* b1 = (const float*)d_in[2];
    const float* w2 = (const float*)d_in[3];
    const float* b2 = (const float*)d_in[4];
    const float* w3 = (const float*)d_in[5];
    const float* b3 = (const float*)d_in[6];
    const float* w4 = (const float*)d_in[7];
    const float* b4 = (const float*)d_in[8];
    const float* w5 = (const float*)d_in[9];
    const float* b5 = (const float*)d_in[10];
    float* out = (float*)d_out;

    char* ws = (char*)d_ws;
    float* hi       = (float*)(ws);                                   // 1 MB
    float* hcb      = (float*)(ws + (1u << 20));                      // 1 MB
    short* w2t      = (short*)(ws + (2u << 20));                      // 128 KB
    float* partials = (float*)(ws + (2u << 20) + (1u << 18));         // 512 KB

    prep<<<1280, 256, 0, stream>>>(in, w1, b1, w2, hi, hcb, w2t);
    big<<<512, 256, 0, stream>>>(hi, hcb, w2t, b2, partials);
    finalK<<<1, 512, 0, stream>>>(partials, w3, b3, w4, b4, w5, b5, out);
}

// Round 9
// 112.522 us; speedup vs baseline: 1.9027x; 1.3186x over previous
//
#include <hip/hip_runtime.h>

// B=2, D=64, N=512, H=256, OUT=64
// mid[b] = sum_{c,i} relu( relu(hi[b,i,:]+hcb[b,c,:]) @ w2 + b2 ) @ w3 + N^2*b3
// out = relu(mid @ w4 + b4) @ w5 + b5
//
// big v9: 128-thread blocks (2 waves). Block tile = 32 pair-rows x 128 cols
// (col-half per block). Wave = 32 rows x 64 cols: acc 2xf32x16 (32 regs),
// bfr 128 regs, A-tile 16KB LDS dbuf. Each wave reads the A tile once
// (1KB/row LDS, half of R1). R1-proven gen pattern, 1 barrier/tile.

using f32x16  = __attribute__((ext_vector_type(16))) float;
using short8  = __attribute__((ext_vector_type(8))) short;
using float2v = __attribute__((ext_vector_type(2))) float;

__device__ __forceinline__ short f2bf(float f) {
    unsigned u = __float_as_uint(f);
    unsigned r = u + 0x7FFFu + ((u >> 16) & 1u);   // RNE
    return (short)(r >> 16);
}

// ---- prep (merged): blocks [0,1024): hi/hcb; blocks [1024,1280): w2t transpose
__global__ __launch_bounds__(256) void prep(const float* __restrict__ in,
                                            const float* __restrict__ w1,
                                            const float* __restrict__ b1,
                                            const float* __restrict__ w2,
                                            float* __restrict__ hi,
                                            float* __restrict__ hcb,
                                            short* __restrict__ w2t) {
    int tid = threadIdx.x;
    int bidx = blockIdx.x;
    if (bidx < 1024) {
        int b = bidx >> 9, n = bidx & 511;
        __shared__ float xs[64];
        if (tid < 64) xs[tid] = in[(size_t)(b * 64 + tid) * 512 + n];
        __syncthreads();
        float a0 = 0.f, a1 = 0.f;
#pragma unroll 8
        for (int d = 0; d < 64; ++d) {
            float xv = xs[d];
            a0 += xv * w1[d * 256 + tid];
            a1 += xv * w1[(64 + d) * 256 + tid];
        }
        size_t o = (size_t)(b * 512 + n) * 256 + tid;
        hi[o]  = a0;
        hcb[o] = a1 + b1[tid];
    } else {
        int idx = (bidx - 1024) * 256 + tid;
        int n = idx & 255, k = idx >> 8;
        w2t[n * 256 + k] = f2bf(w2[k * 256 + n]);
    }
}

// ---- big v9: 1024 blocks x 128 thr. bid -> (b, ch, ih, cq). 32 tiles/block.
__global__ __launch_bounds__(128, 2) void big(const float* __restrict__ hi,
                                              const float* __restrict__ hcb,
                                              const short* __restrict__ w2t,
                                              const float* __restrict__ b2,
                                              float* __restrict__ partials) {
    __shared__ __align__(16) unsigned tA[2][32 * 128];   // 2 x 16 KB (32 rows x 512B)

    const int tid = threadIdx.x;                // 0..127
    const int bid = blockIdx.x;                 // [0,1024)
    const int b  = bid >> 9, ch = (bid >> 8) & 1, ih = (bid >> 7) & 1, cq = bid & 127;

    const float* __restrict__ hib  = hi  + (size_t)b * 131072;
    const float* __restrict__ hcbb = hcb + (size_t)b * 131072;

    const int cp = tid;                          // gen: K-col pair (2cp, 2cp+1)
    const int w = tid >> 6, lane = tid & 63;     // MFMA mapping
    const int h = lane >> 5, l31 = lane & 31, l7 = lane & 7;
    const int colabs0 = ch * 128 + w * 64;

    // context rows (4, fixed per block)
    float2v cv2[4];
#pragma unroll
    for (int j = 0; j < 4; ++j)
        cv2[j] = *reinterpret_cast<const float2v*>(
            &hcbb[(size_t)(cq * 4 + j) * 256 + 2 * cp]);

    // persistent B fragments: 64 cols x K=256 bf16 per wave = 128 VGPRs
    short8 bfr[2][16];
    const short8* w2v = reinterpret_cast<const short8*>(w2t);
#pragma unroll
    for (int cb = 0; cb < 2; ++cb)
#pragma unroll
        for (int kk = 0; kk < 16; ++kk)
            bfr[cb][kk] = w2v[(size_t)(colabs0 + cb * 32 + l31) * 32 + kk * 2 + h];

    const float b2v0 = b2[colabs0 + l31];
    const float b2v1 = b2[colabs0 + 32 + l31];
    float psum0 = 0.f, psum1 = 0.f;

    const int cbase = cp >> 2, woff = cp & 3;

    // gen tile t: rows r = c'*8+i' (c'=p>>3, i'=p&7), i-octet = ih*32+t
    auto gen = [&](int t, unsigned* __restrict__ buf) {
        const float* hs = &hib[(size_t)((ih * 32 + t) * 8) * 256 + 2 * cp];
        float2v hv2[8];
#pragma unroll
        for (int j = 0; j < 8; ++j)
            hv2[j] = *reinterpret_cast<const float2v*>(hs + (size_t)j * 256);
#pragma unroll
        for (int p = 0; p < 32; ++p) {
            float ax = hv2[p & 7][0] + cv2[p >> 3][0];
            float ay = hv2[p & 7][1] + cv2[p >> 3][1];
            ax = fmaxf(ax, 0.f);
            ay = fmaxf(ay, 0.f);
            unsigned pk;
            asm("v_cvt_pk_bf16_f32 %0, %1, %2" : "=v"(pk) : "v"(ax), "v"(ay));
            buf[p * 128 + (((cbase ^ (p & 7)) << 2) + woff)] = pk;
        }
    };

    gen(0, tA[0]);
    __syncthreads();

#pragma unroll 1
    for (int t = 0; t < 32; ++t) {
        const int cur = t & 1;
        if (t < 31) gen(t + 1, tA[cur ^ 1]);

        const short8* __restrict__ tAv = reinterpret_cast<const short8*>(tA[cur]);
        f32x16 A0, A1;
#pragma unroll
        for (int e = 0; e < 16; ++e) { A0[e] = b2v0; A1[e] = b2v1; }

#pragma unroll
        for (int kk = 0; kk < 16; ++kk) {
            const int sc = (kk * 2 + h) ^ l7;
            short8 a = tAv[l31 * 32 + sc];
            __builtin_amdgcn_s_setprio(1);
            A0 = __builtin_amdgcn_mfma_f32_32x32x16_bf16(a, bfr[0][kk], A0, 0, 0, 0);
            A1 = __builtin_amdgcn_mfma_f32_32x32x16_bf16(a, bfr[1][kk], A1, 0, 0, 0);
            __builtin_amdgcn_s_setprio(0);
        }

        float s0 = 0.f, s1 = 0.f;
#pragma unroll
        for (int e = 0; e < 16; ++e) {
            s0 += fmaxf(A0[e], 0.f);
            s1 += fmaxf(A1[e], 0.f);
        }
        psum0 += s0;
        psum1 += s1;
        __syncthreads();
    }

    psum0 += __shfl_xor(psum0, 32);
    psum1 += __shfl_xor(psum1, 32);
    if (h == 0) {
        partials[(size_t)bid * 128 + w * 64 + l31]      = psum0;
        partials[(size_t)bid * 128 + w * 64 + 32 + l31] = psum1;
    }
}

// ---- final: reduce 1024x128 partials + tail MLP, both batches (512 threads)
__global__ __launch_bounds__(512) void finalK(const float* __restrict__ partials,
                                              const float* __restrict__ w3,
                                              const float* __restrict__ b3,
                                              const float* __restrict__ w4,
                                              const float* __restrict__ b4,
                                              const float* __restrict__ w5,
                                              const float* __restrict__ b5,
                                              float* __restrict__ out) {
    __shared__ float su[2][256], mid[2][256], o[2][256];
    int tid = threadIdx.x;
    int b = tid >> 8, c = tid & 255;
    int ch = c >> 7, x = c & 127;
    const float* pb = partials + ((size_t)(b * 512 + ch * 256)) * 128 + x;
    float s = 0.f;
#pragma unroll 8
    for (int r = 0; r < 256; ++r) s += pb[(size_t)r * 128];
    su[b][c] = s;
    __syncthreads();
    float m = 262144.0f * b3[c];
    for (int k = 0; k < 256; ++k) m += su[b][k] * w3[k * 256 + c];
    mid[b][c] = m;
    __syncthreads();
    float ov = b4[c];
    for (int k = 0; k < 256; ++k) ov += mid[b][k] * w4[k * 256 + c];
    o[b][c] = fmaxf(ov, 0.f);
    __syncthreads();
    if (c < 64) {
        float r = b5[c];
        for (int k = 0; k < 256; ++k) r += o[b][k] * w5[k * 64 + c];
        out[b * 64 + c] = r;
    }
}

extern "C" void kernel_launch(void* const* d_in, const int* in_sizes, int n_in,
                              void* d_out, int out_size, void* d_ws, size_t ws_size,
                              hipStream_t stream) {
    const float* in = (const float*)d_in[0];
    const float* w1 = (const float*)d_in[1];
    const float* b1 = (const float*)d_in[2];
    const float* w2 = (const float*)d_in[3];
    const float* b2 = (const float*)d_in[4];
    const float* w3 = (const float*)d_in[5];
    const float* b3 = (const float*)d_in[6];
    const float* w4 = (const float*)d_in[7];
    const float* b4 = (const float*)d_in[8];
    const float* w5 = (const float*)d_in[9];
    const float* b5 = (const float*)d_in[10];
    float* out = (float*)d_out;

    char* ws = (char*)d_ws;
    float* hi       = (float*)(ws);                                   // 1 MB
    float* hcb      = (float*)(ws + (1u << 20));                      // 1 MB
    short* w2t      = (short*)(ws + (2u << 20));                      // 128 KB
    float* partials = (float*)(ws + (2u << 20) + (1u << 18));         // 512 KB

    prep<<<1280, 256, 0, stream>>>(in, w1, b1, w2, hi, hcb, w2t);
    big<<<1024, 128, 0, stream>>>(hi, hcb, w2t, b2, partials);
    finalK<<<1, 512, 0, stream>>>(partials, w3, b3, w4, b4, w5, b5, out);
}